// Round 1
// baseline (2256.132 us; speedup 1.0000x reference)
//
#include <hip/hip_runtime.h>
#include <stdint.h>

// SimpleRNN: B=64, S=2048, INPUT=256, HID=256
// d_in: x [64][2048][256] f32, h0 [64][256] f32, W [256][512] f32, b [256] f32
// d_out: output [64][2048][256] f32, then h_last [64][256] f32
//
// Kernel A: xp = X*Wx^T + b  written INTO d_out's output region (in-place scratch).
// Kernel B: sequential scan, reads xp[b][t][:], overwrites with h_t = sigmoid(xp + h*Wh^T).

#define S_LEN 2048
#define HID 256
#define OUT_ELEMS (64 * 2048 * 256)

typedef __attribute__((ext_vector_type(8))) short short8;
typedef __attribute__((ext_vector_type(4))) float float4_t;

__device__ inline unsigned short f2bf(float f) {
    union { float f; unsigned u; } c; c.f = f;
    unsigned u = c.u;
    return (unsigned short)((u + 0x7FFFu + ((u >> 16) & 1u)) >> 16);  // RNE
}

__device__ inline short8 load_bf8(const float* __restrict__ p) {
    float4_t lo = *(const float4_t*)p;
    float4_t hi = *(const float4_t*)(p + 4);
    short8 r;
    r[0] = (short)f2bf(lo[0]); r[1] = (short)f2bf(lo[1]);
    r[2] = (short)f2bf(lo[2]); r[3] = (short)f2bf(lo[3]);
    r[4] = (short)f2bf(hi[0]); r[5] = (short)f2bf(hi[1]);
    r[6] = (short)f2bf(hi[2]); r[7] = (short)f2bf(hi[3]);
    return r;
}

// ---------------- Kernel A: x_proj GEMM (bf16 MFMA, register fragments) ----------
// grid 512 blocks x 256 thr; each block does 16 M-tiles of 16 rows; wave w owns cols 64w..64w+63.
__global__ __launch_bounds__(256, 2) void xproj_kernel(
    const float* __restrict__ X,    // [131072][256]
    const float* __restrict__ W,    // [256][512]  (Wx = cols 0..255)
    const float* __restrict__ bias, // [256]
    float* __restrict__ XP)         // [131072][256]  (= d_out output region)
{
    const int lane = threadIdx.x & 63;
    const int wv   = threadIdx.x >> 6;   // 0..3
    const int n0   = wv * 64;
    const int lrow = lane & 15;
    const int g    = lane >> 4;          // 0..3

    // B fragments: B[k][n] = Wx[n][k]; lane holds 8 contiguous k of row n0+16nt+lrow
    short8 bq[4][8];
#pragma unroll
    for (int nt = 0; nt < 4; ++nt) {
        const float* wr = W + (n0 + 16 * nt + lrow) * 512;
#pragma unroll
        for (int kt = 0; kt < 8; ++kt)
            bq[nt][kt] = load_bf8(wr + 32 * kt + 8 * g);
    }
    float bias_v[4];
#pragma unroll
    for (int nt = 0; nt < 4; ++nt) bias_v[nt] = bias[n0 + 16 * nt + lrow];

    int m0 = blockIdx.x * 256;
#pragma unroll 1
    for (int i = 0; i < 16; ++i, m0 += 16) {
        short8 aq[8];
        const float* xr = X + (m0 + lrow) * 256;
#pragma unroll
        for (int kt = 0; kt < 8; ++kt)
            aq[kt] = load_bf8(xr + 32 * kt + 8 * g);
#pragma unroll
        for (int nt = 0; nt < 4; ++nt) {
            float4_t acc = {bias_v[nt], bias_v[nt], bias_v[nt], bias_v[nt]};
#pragma unroll
            for (int kt = 0; kt < 8; ++kt)
                acc = __builtin_amdgcn_mfma_f32_16x16x32_bf16(aq[kt], bq[nt][kt], acc, 0, 0, 0);
            // D: row = 4g+r, col = lrow (within tile)
            float* orow = XP + (m0 + 4 * g) * 256 + (n0 + 16 * nt + lrow);
#pragma unroll
            for (int r = 0; r < 4; ++r)
                orow[r * 256] = acc[r];
        }
    }
}

// ---------------- Kernel B: sequential scan -------------------------------------
// grid 4 blocks x 256 thr (4 waves). Block bg: batches 16bg..16bg+15 (= MFMA M dim).
// Wave w: hidden cols 64w..64w+63. Wh^T B-fragments resident in VGPRs.
// h double-buffered in LDS as bf16, XOR-swizzled (^(b&7)<<4 bytes).

#define STEP(T, XPA, CUR, NXT)                                                      \
  {                                                                                 \
    short8 aq[8];                                                                   \
    _Pragma("unroll")                                                               \
    for (int kt = 0; kt < 8; ++kt) {                                                \
        int idx = (lrow * 256 + 32 * kt + 8 * g) ^ ((lrow & 7) << 3);               \
        aq[kt] = *(const short8*)&hb[CUR][idx];                                     \
    }                                                                               \
    float4_t acc[4];                                                                \
    _Pragma("unroll")                                                               \
    for (int nt = 0; nt < 4; ++nt) {                                                \
        acc[nt] = (float4_t){XPA[nt * 4 + 0], XPA[nt * 4 + 1],                      \
                             XPA[nt * 4 + 2], XPA[nt * 4 + 3]};                     \
        _Pragma("unroll")                                                           \
        for (int kt = 0; kt < 8; ++kt)                                              \
            acc[nt] = __builtin_amdgcn_mfma_f32_16x16x32_bf16(aq[kt], bq[nt][kt],   \
                                                              acc[nt], 0, 0, 0);    \
    }                                                                               \
    /* prefetch xp for T+2 (stays in-bounds of d_out even at T+2=2049) */           \
    _Pragma("unroll")                                                               \
    for (int nt = 0; nt < 4; ++nt) {                                                \
        _Pragma("unroll")                                                           \
        for (int r = 0; r < 4; ++r)                                                 \
            XPA[nt * 4 + r] =                                                       \
                OUT[((b0 + 4 * g + r) * S_LEN + (T + 2)) * HID + n0 + 16 * nt + lrow]; \
    }                                                                               \
    _Pragma("unroll")                                                               \
    for (int nt = 0; nt < 4; ++nt) {                                                \
        _Pragma("unroll")                                                           \
        for (int r = 0; r < 4; ++r) {                                               \
            float p = acc[nt][r];                                                   \
            float s = __builtin_amdgcn_rcpf(                                        \
                1.0f + __builtin_amdgcn_exp2f(p * -1.44269504088896f));             \
            int bb = 4 * g + r;                                                     \
            int j  = n0 + 16 * nt + lrow;                                           \
            OUT[((b0 + bb) * S_LEN + (T)) * HID + j] = s;                           \
            if ((T) == S_LEN - 1)                                                   \
                OUT[OUT_ELEMS + (b0 + bb) * HID + j] = s;                           \
            hb[NXT][((bb * 256 + j) ^ ((bb & 7) << 3))] = f2bf(s);                  \
        }                                                                           \
    }                                                                               \
    __syncthreads();                                                                \
  }

__global__ __launch_bounds__(256, 1) void rnn_scan_kernel(
    const float* __restrict__ W,   // [256][512]  (Wh = cols 256..511)
    const float* __restrict__ H0,  // [64][256]
    float* OUT)                    // d_out base
{
    __shared__ unsigned short hb[2][16 * 256];
    const int lane = threadIdx.x & 63;
    const int wv   = threadIdx.x >> 6;
    const int n0   = wv * 64;
    const int lrow = lane & 15;
    const int g    = lane >> 4;
    const int b0   = blockIdx.x * 16;

    // Wh^T B-fragments: B[k][n] = Wh[n][k]
    short8 bq[4][8];
#pragma unroll
    for (int nt = 0; nt < 4; ++nt) {
        const float* wr = W + (n0 + 16 * nt + lrow) * 512 + 256;
#pragma unroll
        for (int kt = 0; kt < 8; ++kt)
            bq[nt][kt] = load_bf8(wr + 32 * kt + 8 * g);
    }

    // init h buffer 0 from H0 (swizzled bf16)
    for (int idx = threadIdx.x; idx < 4096; idx += 256) {
        int bb = idx >> 8, k = idx & 255;
        hb[0][((bb * 256 + k) ^ ((bb & 7) << 3))] = f2bf(H0[(b0 + bb) * 256 + k]);
    }
    __syncthreads();

    // xp prefetch, distance 2
    float xp0[16], xp1[16];
#pragma unroll
    for (int nt = 0; nt < 4; ++nt)
#pragma unroll
        for (int r = 0; r < 4; ++r) {
            int j = n0 + 16 * nt + lrow;
            xp0[nt * 4 + r] = OUT[((b0 + 4 * g + r) * S_LEN + 0) * HID + j];
            xp1[nt * 4 + r] = OUT[((b0 + 4 * g + r) * S_LEN + 1) * HID + j];
        }

#pragma unroll 1
    for (int t = 0; t < S_LEN; t += 2) {
        STEP(t, xp0, 0, 1)
        STEP(t + 1, xp1, 1, 0)
    }
}

extern "C" void kernel_launch(void* const* d_in, const int* in_sizes, int n_in,
                              void* d_out, int out_size, void* d_ws, size_t ws_size,
                              hipStream_t stream) {
    const float* x    = (const float*)d_in[0];
    const float* h0   = (const float*)d_in[1];
    const float* W    = (const float*)d_in[2];
    const float* bias = (const float*)d_in[3];
    float* out = (float*)d_out;

    xproj_kernel<<<512, 256, 0, stream>>>(x, W, bias, out);
    rnn_scan_kernel<<<4, 256, 0, stream>>>(W, h0, out);
}

// Round 2
// 990.091 us; speedup vs baseline: 2.2787x; 2.2787x over previous
//
#include <hip/hip_runtime.h>
#include <stdint.h>

// SimpleRNN: B=64, S=2048, INPUT=256, HID=256
// d_in: x [64][2048][256] f32, h0 [64][256] f32, W [256][512] f32, b [256] f32
// d_out: output [64][2048][256] f32, then h_last [64][256] f32
//
// Kernel A: xp = X*Wx^T + b  written INTO d_out's output region (in-place scratch).
// Kernel B: 64 blocks (1 batch each), sequential scan overwriting xp with h_t.

#define S_LEN 2048
#define HID 256
#define OUT_ELEMS (64 * 2048 * 256)

typedef __attribute__((ext_vector_type(8))) short short8;
typedef __attribute__((ext_vector_type(4))) float float4_t;

__device__ inline unsigned short f2bf(float f) {
    union { float f; unsigned u; } c; c.f = f;
    unsigned u = c.u;
    return (unsigned short)((u + 0x7FFFu + ((u >> 16) & 1u)) >> 16);  // RNE
}

__device__ inline short8 load_bf8(const float* __restrict__ p) {
    float4_t lo = *(const float4_t*)p;
    float4_t hi = *(const float4_t*)(p + 4);
    short8 r;
    r[0] = (short)f2bf(lo[0]); r[1] = (short)f2bf(lo[1]);
    r[2] = (short)f2bf(lo[2]); r[3] = (short)f2bf(lo[3]);
    r[4] = (short)f2bf(hi[0]); r[5] = (short)f2bf(hi[1]);
    r[6] = (short)f2bf(hi[2]); r[7] = (short)f2bf(hi[3]);
    return r;
}

// ---------------- Kernel A: x_proj GEMM (bf16 MFMA, register fragments) ----------
// grid 512 blocks x 256 thr; each block does 16 M-tiles of 16 rows; wave w owns cols 64w..64w+63.
__global__ __launch_bounds__(256, 2) void xproj_kernel(
    const float* __restrict__ X,    // [131072][256]
    const float* __restrict__ W,    // [256][512]  (Wx = cols 0..255)
    const float* __restrict__ bias, // [256]
    float* __restrict__ XP)         // [131072][256]  (= d_out output region)
{
    const int lane = threadIdx.x & 63;
    const int wv   = threadIdx.x >> 6;   // 0..3
    const int n0   = wv * 64;
    const int lrow = lane & 15;
    const int g    = lane >> 4;          // 0..3

    // B fragments: B[k][n] = Wx[n][k]; lane holds 8 contiguous k of row n0+16nt+lrow
    short8 bq[4][8];
#pragma unroll
    for (int nt = 0; nt < 4; ++nt) {
        const float* wr = W + (n0 + 16 * nt + lrow) * 512;
#pragma unroll
        for (int kt = 0; kt < 8; ++kt)
            bq[nt][kt] = load_bf8(wr + 32 * kt + 8 * g);
    }
    float bias_v[4];
#pragma unroll
    for (int nt = 0; nt < 4; ++nt) bias_v[nt] = bias[n0 + 16 * nt + lrow];

    int m0 = blockIdx.x * 256;
#pragma unroll 1
    for (int i = 0; i < 16; ++i, m0 += 16) {
        short8 aq[8];
        const float* xr = X + (m0 + lrow) * 256;
#pragma unroll
        for (int kt = 0; kt < 8; ++kt)
            aq[kt] = load_bf8(xr + 32 * kt + 8 * g);
#pragma unroll
        for (int nt = 0; nt < 4; ++nt) {
            float4_t acc = {bias_v[nt], bias_v[nt], bias_v[nt], bias_v[nt]};
#pragma unroll
            for (int kt = 0; kt < 8; ++kt)
                acc = __builtin_amdgcn_mfma_f32_16x16x32_bf16(aq[kt], bq[nt][kt], acc, 0, 0, 0);
            // D: row = 4g+r, col = lrow (within tile)
            float* orow = XP + (m0 + 4 * g) * 256 + (n0 + 16 * nt + lrow);
#pragma unroll
            for (int r = 0; r < 4; ++r)
                orow[r * 256] = acc[r];
        }
    }
}

// ---------------- Kernel B: sequential scan, 1 batch per block -------------------
// 64 blocks x 256 thr (4 waves). Block b: batch b. Wave wv: hidden cols 64wv..+63.
// Since every A-row of the MFMA is fed the same h (address indep of lrow), D rows
// are replicated -> every lane holds out[n0+16g+lrow] = out[n0+lane]: coalesced
// store + contiguous LDS writeback. A-reads are 16-lane broadcasts (conflict-free).

#define STEP(T, XPB, CUR, NXT)                                                      \
  {                                                                                 \
    short8 aq[8];                                                                   \
    _Pragma("unroll")                                                               \
    for (int kt = 0; kt < 8; ++kt)                                                  \
        aq[kt] = *(const short8*)&hb[CUR][32 * kt + 8 * g];                         \
    float4_t a0 = {XPB[0], XPB[0], XPB[0], XPB[0]};                                 \
    float4_t a1 = {XPB[1], XPB[1], XPB[1], XPB[1]};                                 \
    float4_t a2 = {XPB[2], XPB[2], XPB[2], XPB[2]};                                 \
    float4_t a3 = {XPB[3], XPB[3], XPB[3], XPB[3]};                                 \
    _Pragma("unroll")                                                               \
    for (int kt = 0; kt < 8; ++kt) {                                                \
        a0 = __builtin_amdgcn_mfma_f32_16x16x32_bf16(aq[kt], bq[0][kt], a0, 0, 0, 0); \
        a1 = __builtin_amdgcn_mfma_f32_16x16x32_bf16(aq[kt], bq[1][kt], a1, 0, 0, 0); \
        a2 = __builtin_amdgcn_mfma_f32_16x16x32_bf16(aq[kt], bq[2][kt], a2, 0, 0, 0); \
        a3 = __builtin_amdgcn_mfma_f32_16x16x32_bf16(aq[kt], bq[3][kt], a3, 0, 0, 0); \
    }                                                                               \
    /* prefetch xp for T+4 (reads stay within d_out even past the last row) */      \
    _Pragma("unroll")                                                               \
    for (int nt = 0; nt < 4; ++nt)                                                  \
        XPB[nt] = xpb[((T) + 4) * HID + 16 * nt];                                   \
    float p01 = (g & 1) ? a1[0] : a0[0];                                            \
    float p23 = (g & 1) ? a3[0] : a2[0];                                            \
    float p   = (g & 2) ? p23 : p01;                                                \
    float s = __builtin_amdgcn_rcpf(                                                \
        1.0f + __builtin_amdgcn_exp2f(p * -1.44269504088896f));                     \
    OUT[obase + (T) * HID] = s;                                                     \
    if ((T) == S_LEN - 1)                                                           \
        OUT[OUT_ELEMS + b * HID + n0 + lane] = s;                                   \
    hb[NXT][n0 + lane] = f2bf(s);                                                   \
    __syncthreads();                                                                \
  }

__global__ __launch_bounds__(256, 1) void rnn_scan_kernel(
    const float* __restrict__ W,   // [256][512]  (Wh = cols 256..511)
    const float* __restrict__ H0,  // [64][256]
    float* __restrict__ OUT)       // d_out base
{
    __shared__ unsigned short hb[2][256];
    const int lane = threadIdx.x & 63;
    const int wv   = threadIdx.x >> 6;
    const int n0   = wv * 64;
    const int lrow = lane & 15;
    const int g    = lane >> 4;
    const int b    = blockIdx.x;   // batch index

    // Wh^T B-fragments: B[k][n] = Wh[n][k]
    short8 bq[4][8];
#pragma unroll
    for (int nt = 0; nt < 4; ++nt) {
        const float* wr = W + (n0 + 16 * nt + lrow) * 512 + 256;
#pragma unroll
        for (int kt = 0; kt < 8; ++kt)
            bq[nt][kt] = load_bf8(wr + 32 * kt + 8 * g);
    }

    // init h buffer 0 from H0 (plain contiguous bf16)
    hb[0][threadIdx.x] = f2bf(H0[b * HID + threadIdx.x]);
    __syncthreads();

    const float* xpb = OUT + (size_t)b * S_LEN * HID + n0 + lrow;  // + t*HID + 16*nt
    const int obase  = b * S_LEN * HID + n0 + lane;

    // xp prefetch, distance 4
    float xp0[4], xp1[4], xp2[4], xp3[4];
#pragma unroll
    for (int nt = 0; nt < 4; ++nt) {
        xp0[nt] = xpb[0 * HID + 16 * nt];
        xp1[nt] = xpb[1 * HID + 16 * nt];
        xp2[nt] = xpb[2 * HID + 16 * nt];
        xp3[nt] = xpb[3 * HID + 16 * nt];
    }

#pragma unroll 1
    for (int t = 0; t < S_LEN; t += 4) {
        STEP(t,     xp0, 0, 1)
        STEP(t + 1, xp1, 1, 0)
        STEP(t + 2, xp2, 0, 1)
        STEP(t + 3, xp3, 1, 0)
    }
}

extern "C" void kernel_launch(void* const* d_in, const int* in_sizes, int n_in,
                              void* d_out, int out_size, void* d_ws, size_t ws_size,
                              hipStream_t stream) {
    const float* x    = (const float*)d_in[0];
    const float* h0   = (const float*)d_in[1];
    const float* W    = (const float*)d_in[2];
    const float* bias = (const float*)d_in[3];
    float* out = (float*)d_out;

    xproj_kernel<<<512, 256, 0, stream>>>(x, W, bias, out);
    rnn_scan_kernel<<<64, 256, 0, stream>>>(W, h0, out);
}